// Round 9
// baseline (387.168 us; speedup 1.0000x reference)
//
#include <hip/hip_runtime.h>
#include <hip/hip_fp16.h>
#include <cstdint>
#include <cstddef>

#define NB   4096   // batch
#define ND   128    // feature dim
#define OUTW 16384  // 4*NB output row width
#define CG   16     // col groups for the sum pass
#define IT   8      // 64-col tiles per sum block

// 10 * log2(e): logits = cos/T = 10*acc; exp(10a-10) = 2^(K2*a - K2)
#define K2   14.4269504088896341f

typedef _Float16 f16;
typedef __attribute__((ext_vector_type(2))) _Float16 f16x2;
typedef __attribute__((ext_vector_type(8))) _Float16 f16x8;
typedef __attribute__((ext_vector_type(4))) float   f32x4;

// ---------------------------------------------------------------------------
// Kernel 1: l2-normalize z1,z2 rows, cast to f16; also zero rowsum (8192 f32).
// ---------------------------------------------------------------------------
__global__ __launch_bounds__(256) void nrm_kernel(const float* __restrict__ z1,
                                                  const float* __restrict__ z2,
                                                  f16* __restrict__ ab,
                                                  float* __restrict__ rowsum) {
  if (threadIdx.x < 4) rowsum[blockIdx.x * 4 + threadIdx.x] = 0.0f;
  int row  = blockIdx.x * 4 + (threadIdx.x >> 6);
  int lane = threadIdx.x & 63;
  const float* src = (row < NB) ? (z1 + (size_t)row * ND)
                                : (z2 + (size_t)(row - NB) * ND);
  float2 v = ((const float2*)src)[lane];
  float ss = v.x * v.x + v.y * v.y;
#pragma unroll
  for (int off = 32; off; off >>= 1) ss += __shfl_xor(ss, off);
  float r = rsqrtf(fmaxf(ss, 1e-12f));
  f16x2 h;
  h.x = (f16)(v.x * r);
  h.y = (f16)(v.y * r);
  ((f16x2*)(ab + (size_t)row * ND))[lane] = h;
}

// ---------------------------------------------------------------------------
// Sum pass: EXACT R5-verified pass<false> (grid CG x 64). ~15 us, leave alone.
// ---------------------------------------------------------------------------
__global__ __launch_bounds__(256, 2) void sum_kernel(const f16* __restrict__ ab,
                                                     float* __restrict__ rowsum) {
  __shared__ f16 Bs[2][64 * ND];   // 2 x 16 KB

  const int t    = threadIdx.x;
  const int wave = t >> 6;
  const int lane = t & 63;
  const int wr   = wave >> 1;
  const int wc   = wave & 1;
  const int quad = lane >> 4;
  const int l16  = lane & 15;

  const int rt    = blockIdx.y;            // 0..63
  const int type  = rt >> 5;               // 0 = part1 (query a), 1 = part2 (b)
  const int r0    = (rt & 31) * 128;       // query row base in [0,4096)
  const int g     = blockIdx.x;            // 0..CG-1
  const int h2    = (g >= CG / 2) ? 1 : 0; // own-matrix half (diag masked)
  const int cbase = (g * 512) & (NB - 1);  // within-matrix col base
  const f16* Q  = ab + (size_t)type * NB * ND;
  const f16* Kp = ab + (size_t)(h2 ? type : (type ^ 1)) * NB * ND;

  f16x8 af[4][4];
  {
    const int arow = r0 + wr * 64 + l16;
#pragma unroll
    for (int mi = 0; mi < 4; ++mi)
#pragma unroll
      for (int ks = 0; ks < 4; ++ks)
        af[mi][ks] = *(const f16x8*)(Q + (size_t)(arow + mi * 16) * ND +
                                     ks * 32 + quad * 8);
  }

  const int sub = t >> 4;   // 0..15
  const int oct = t & 15;
  auto stage_b = [&](f16* buf, int kc0) {
#pragma unroll
    for (int i = 0; i < 4; ++i) {
      int rowl = i * 16 + sub;
      int goct = oct ^ (rowl & 15);
      __builtin_amdgcn_global_load_lds(
          (const __attribute__((address_space(1))) void*)(
              Kp + (size_t)(kc0 + rowl) * ND + goct * 8),
          (__attribute__((address_space(3))) void*)(buf + rowl * ND + oct * 8),
          16, 0, 0);
    }
  };

  float ps[4];
#pragma unroll
  for (int mi = 0; mi < 4; ++mi) ps[mi] = 0.0f;

  stage_b(Bs[0], cbase);
  __syncthreads();

  for (int it = 0; it < IT; ++it) {
    if (it + 1 < IT) stage_b(Bs[(it + 1) & 1], cbase + (it + 1) * 64);

    const f16* buf = Bs[it & 1];
    f32x4 acc[4][2] = {};
#pragma unroll
    for (int ks = 0; ks < 4; ++ks) {
      int sw = (((ks * 4 + quad) ^ l16)) * 8;
      f16x8 bf0 = *(const f16x8*)(buf + (wc * 32 + l16) * ND + sw);
      f16x8 bf1 = *(const f16x8*)(buf + (wc * 32 + 16 + l16) * ND + sw);
#pragma unroll
      for (int mi = 0; mi < 4; ++mi) {
        acc[mi][0] = __builtin_amdgcn_mfma_f32_16x16x32_f16(bf0, af[mi][ks],
                                                            acc[mi][0], 0, 0, 0);
        acc[mi][1] = __builtin_amdgcn_mfma_f32_16x16x32_f16(bf1, af[mi][ks],
                                                            acc[mi][1], 0, 0, 0);
      }
    }

    const int c0m = cbase + it * 64;
    const bool dtile = h2 && (c0m == r0 || c0m == r0 + 64);

#pragma unroll
    for (int mi = 0; mi < 4; ++mi) {
      const int row_l = wr * 64 + mi * 16 + l16;
#pragma unroll
      for (int ni = 0; ni < 2; ++ni) {
        const int cq = wc * 32 + ni * 16 + quad * 4;
#pragma unroll
        for (int r = 0; r < 4; ++r) {
          float e = __builtin_amdgcn_exp2f(fmaf(acc[mi][ni][r], K2, -K2));
          if (dtile && (c0m + cq + r == r0 + row_l)) e = 0.0f;
          ps[mi] += e;
        }
      }
    }
    __syncthreads();
  }

#pragma unroll
  for (int mi = 0; mi < 4; ++mi) {
    float v = ps[mi];
    v += __shfl_xor(v, 16);
    v += __shfl_xor(v, 32);
    if (quad == 0) {
      int row_l = wr * 64 + mi * 16 + l16;
      atomicAdd(&rowsum[rt * 128 + row_l], v);
    }
  }
}

// ---------------------------------------------------------------------------
// Write pass, DRAM-burst-optimized: 256 blocks = (strip 0..127: 32 rows) x
// (half 0: part1 cols 0..8191 / half 1: part2 cols 8192..16383).
// Per block: 128 col-tiles of 64; epilogue deposits exp-values into a 32 KB
// LDS tile ob[32][256] (f32, XOR-swizzled); every 4 tiles flush as 32 rows x
// 1 KB SEQUENTIAL nontemporal bursts (one wave-store per row) -> DRAM-page-
// sized writes instead of 256 B fragments.
// Wave w owns cols w*16..w*16+15 of each tile; af covers all 32 rows.
// ---------------------------------------------------------------------------
__global__ __launch_bounds__(256, 2) void wr_kernel(const f16* __restrict__ ab,
                                                    float* __restrict__ rowsum,
                                                    float* __restrict__ out) {
  __shared__ f16 Bs[2][64 * ND];     // 32 KB
  __shared__ float ob[32 * 256];     // 32 KB out-buffer (swizzled f32x4 slots)
  __shared__ float cs[32];

  const int t    = threadIdx.x;
  const int w    = t >> 6;           // wave 0..3 = col-quadrant of 64-tile
  const int lane = t & 63;
  const int quad = lane >> 4;
  const int l16  = lane & 15;
  const int sub  = t >> 4;
  const int oct  = t & 15;

  const int half  = blockIdx.x & 1;        // 0 = part1 (Q=a), 1 = part2 (Q=b)
  const int strip = blockIdx.x >> 1;       // 0..127
  const int r0    = strip * 32;

  const f16* Q      = ab + (size_t)half * NB * ND;
  const f16* Kcross = ab + (size_t)(half ^ 1) * NB * ND;  // tiles 0..63
  const f16* Kown   = Q;                                  // tiles 64..127 (diag)

  // A fragments: 32 rows x K128 (all waves load the same, L2-hot).
  f16x8 af[2][4];
#pragma unroll
  for (int mi = 0; mi < 2; ++mi)
#pragma unroll
    for (int ks = 0; ks < 4; ++ks)
      af[mi][ks] = *(const f16x8*)(Q + (size_t)(r0 + mi * 16 + l16) * ND +
                                   ks * 32 + quad * 8);

  auto stage_b = [&](f16* buf, int it) {   // stage tile `it` (0..127)
    const f16* Kp = (it < 64) ? Kcross : Kown;
    const int kc0 = (it & 63) * 64;
#pragma unroll
    for (int i = 0; i < 4; ++i) {
      int rowl = i * 16 + sub;
      int goct = oct ^ (rowl & 15);
      __builtin_amdgcn_global_load_lds(
          (const __attribute__((address_space(1))) void*)(
              Kp + (size_t)(kc0 + rowl) * ND + goct * 8),
          (__attribute__((address_space(3))) void*)(buf + rowl * ND + oct * 8),
          16, 0, 0);
    }
  };

  stage_b(Bs[0], 0);
  if (t < 32) cs[t] = -__log2f(rowsum[half * NB + r0 + t]) - K2;
  __syncthreads();

  for (int it = 0; it < 128; ++it) {
    if (it + 1 < 128) stage_b(Bs[(it + 1) & 1], it + 1);

    const f16* buf = Bs[it & 1];
    f32x4 acc[2] = {};
#pragma unroll
    for (int ks = 0; ks < 4; ++ks) {
      int sw = (((ks * 4 + quad) ^ l16)) * 8;
      f16x8 bf = *(const f16x8*)(buf + (w * 16 + l16) * ND + sw);
#pragma unroll
      for (int mi = 0; mi < 2; ++mi)
        acc[mi] = __builtin_amdgcn_mfma_f32_16x16x32_f16(bf, af[mi][ks],
                                                         acc[mi], 0, 0, 0);
    }

    // diagonal: own-matrix region is tiles 64..127; tile col base (it-64)*64.
    const int cm   = (it - 64) * 64;           // matrix col base if own region
    const bool dtile = (it >= 64) && (cm == (r0 & ~63));

#pragma unroll
    for (int mi = 0; mi < 2; ++mi) {
      const int row32 = mi * 16 + l16;
      const float c = cs[row32];
      f32x4 o;
#pragma unroll
      for (int r = 0; r < 4; ++r) {
        float e = __builtin_amdgcn_exp2f(fmaf(acc[mi][r], K2, c));
        if (dtile && (cm + w * 16 + quad * 4 + r == r0 + row32)) e = 0.0f;
        o[r] = e;
      }
      // logical f32x4 slot within 256-col group: c4 = (it&3)*16 + w*4 + quad
      const int c4 = (it & 3) * 16 + w * 4 + quad;
      const int c4s = c4 ^ (row32 & 7);        // bank swizzle
      *(f32x4*)&ob[row32 * 256 + c4s * 4] = o;
    }
    __syncthreads();                            // Bs prefetch + ob complete

    if ((it & 3) == 3) {
      // flush 32 rows x 1 KB sequential: wave w rows w*8..w*8+7.
      const int fc = (it >> 2) * 256;           // col base within half
#pragma unroll
      for (int rr = 0; rr < 8; ++rr) {
        const int row32 = w * 8 + rr;
        f32x4 v = *(const f32x4*)&ob[row32 * 256 + (lane ^ (row32 & 7)) * 4];
        __builtin_nontemporal_store(
            v, (f32x4*)(out + (size_t)(r0 + row32) * OUTW + half * 8192 + fc +
                        lane * 4));
      }
      __syncthreads();                          // ob free for reuse
    }
  }
}

// ---------------------------------------------------------------------------
extern "C" void kernel_launch(void* const* d_in, const int* in_sizes, int n_in,
                              void* d_out, int out_size, void* d_ws, size_t ws_size,
                              hipStream_t stream) {
  const float* z1 = (const float*)d_in[0];
  const float* z2 = (const float*)d_in[1];
  float* out = (float*)d_out;

  f16* ab = (f16*)d_ws;                                   // 8192x128 f16 = 2 MB
  float* rowsum = (float*)((char*)d_ws + (size_t)8192 * ND * sizeof(f16)); // 32 KB

  nrm_kernel<<<2048, 256, 0, stream>>>(z1, z2, ab, rowsum);
  sum_kernel<<<dim3(CG, 64), 256, 0, stream>>>(ab, rowsum);
  wr_kernel<<<256, 256, 0, stream>>>(ab, rowsum, out);
}